// Round 12
// baseline (283.251 us; speedup 1.0000x reference)
//
#include <hip/hip_runtime.h>
#include <hip/hip_fp16.h>

// WHTConv2D fused: out = Rw(Rh(g(Rh(Rw(x))))) + x ; Rw/Rh = normalized FWHT-256.
// x: (8,64,256,256) f32 -> 512 planes. One 1024-thread block per plane, plane
// staged in LDS fp16, ODD PITCH 129 dwords/row (258 halves, 129 KiB).
// v,T pre-packed (v,|T|) fp16 in d_ws by k_prep.
//
// Round-12: shuffle-free. With pitch 129 dwords, bank = (row + dword_col) % 32,
// so BOTH access orientations are 2 lanes/bank (measured-free):
//   - lanes across 64 consecutive dword-cols at uniform row  (h-passes; = r8 A/C)
//   - lanes across 64 consecutive rows at uniform dword-col  (w-passes; diagonal)
// 7 passes, all fwht16 in registers + b32/u16 LDS only (no shuffles, no b128):
//   P1 w0-fwd (global->LDS) | P2 w1-fwd xSC | P3 h0-fwd |
//   P4 h1-fwd xSC -> g -> h1-inv xSC (== round-8 pass B, proven 0-conflict) |
//   P5 h0-inv | P6 w1-inv | P7 w0-inv xSC + x residual -> out.
// Removes the 640 serial-chained shfl_xor/thread (DS-pipe ~70us) of round-11.

#define NPX    65536   // pixels per plane (global pitch 256)
#define PITCHD 129     // LDS dwords per row (258 halves) -- odd => diagonal banks
#define SC     0.0625f // 1/sqrt(256)

__device__ __forceinline__ unsigned int h2u(__half2 h) {
  union { __half2 h; unsigned int u; } c; c.h = h; return c.u;
}
__device__ __forceinline__ __half2 u2h(unsigned int u) {
  union { __half2 h; unsigned int u; } c; c.u = u; return c.h;
}

// 16-point unnormalized FWHT fully in registers.
__device__ __forceinline__ void fwht16(float f[16]) {
  #pragma unroll
  for (int d = 1; d < 16; d <<= 1) {
    #pragma unroll
    for (int i = 0; i < 16; ++i) {
      if (!(i & d)) {
        float a = f[i], b = f[i | d];
        f[i]     = a + b;
        f[i | d] = a - b;
      }
    }
  }
}

// g term with signed tanh: tanh(a)*relu(|a|-absT)
__device__ __forceinline__ float g_term(float a, float absT) {
  float e  = __builtin_amdgcn_exp2f(a * 2.8853900817779268f);  // exp(2a)
  float th = 1.0f - 2.0f * __builtin_amdgcn_rcpf(e + 1.0f);    // tanh(a)
  float rl = fmaxf(fabsf(a) - absT, 0.0f);                     // fabs = src mod
  return th * rl;
}

// ---- prep: W[p][pix] = half2(v, |T|) packed in one u32 ----
__global__ __launch_bounds__(256) void k_prep(const float* __restrict__ v,
                                              const float* __restrict__ T,
                                              unsigned int* __restrict__ W) {
  const int i = 4 * (blockIdx.x * 256 + threadIdx.x);
  const float4 v4 = *reinterpret_cast<const float4*>(v + i);
  const float4 t4 = *reinterpret_cast<const float4*>(T + i);
  uint4 w;
  w.x = h2u(__floats2half2_rn(v4.x, fabsf(t4.x)));
  w.y = h2u(__floats2half2_rn(v4.y, fabsf(t4.y)));
  w.z = h2u(__floats2half2_rn(v4.z, fabsf(t4.z)));
  w.w = h2u(__floats2half2_rn(v4.w, fabsf(t4.w)));
  *reinterpret_cast<uint4*>(W + i) = w;
}

__global__ __launch_bounds__(1024) void k_fused(const float* __restrict__ x,
                                                const unsigned int* __restrict__ W,
                                                float* __restrict__ out) {
  __shared__ __align__(16) unsigned int SP[256 * PITCHD];   // 129 KiB
  const int tid = threadIdx.x;
  const size_t pbase = (size_t)blockIdx.x * NPX;

  // ---- P1: global load (64B/lane segments) -> fwht16 over w0 -> LDS ----
  // task (h, w1): h = tid&255 (lanes = 64 consecutive h), w1 wave-uniform.
  {
    const int h  = tid & 255;
    const int qq = tid >> 8;                 // 0..3
    #pragma unroll 1
    for (int it = 0; it < 4; ++it) {
      const int w1 = qq * 4 + it;            // 0..15, wave-uniform
      const float* xp = x + pbase + 256 * h + 16 * w1;
      float f[16];
      #pragma unroll
      for (int j = 0; j < 4; ++j) {
        const float4 t4 = *reinterpret_cast<const float4*>(xp + 4 * j);
        f[4*j] = t4.x; f[4*j+1] = t4.y; f[4*j+2] = t4.z; f[4*j+3] = t4.w;
      }
      fwht16(f);
      unsigned int* sp = SP + PITCHD * h + 8 * w1;
      #pragma unroll
      for (int j = 0; j < 8; ++j)            // banks (h + 8w1 + j)%32: free
        sp[j] = h2u(__floats2half2_rn(f[2*j], f[2*j+1]));
    }
  }
  __syncthreads();

  // ---- P2: fwht16 over w1, xSC (Rw fwd complete) ----
  // task (h, c): c = dword within w0-octet (0..7); stride-8-dword reads.
  {
    const int h = tid & 255;
    #pragma unroll 1
    for (int it = 0; it < 2; ++it) {
      const int c = (tid >> 8) + 4 * it;     // 0..7, wave-uniform
      unsigned int* sp = SP + PITCHD * h + c;
      float fA[16], fB[16];
      #pragma unroll
      for (int a = 0; a < 16; ++a) {         // banks (h + 8a + c)%32: free
        const float2 e = __half22float2(u2h(sp[8 * a]));
        fA[a] = e.x; fB[a] = e.y;
      }
      fwht16(fA); fwht16(fB);
      #pragma unroll
      for (int a = 0; a < 16; ++a)
        sp[8 * a] = h2u(__floats2half2_rn(fA[a] * SC, fB[a] * SC));
    }
  }
  __syncthreads();

  // ---- P3: fwht16 over h0 (rows 16g+k), no scale ----
  const int q = tid & 63, g = tid >> 6;
  #pragma unroll 1
  for (int hs = 0; hs < 2; ++hs) {
    const int cd = q + 64 * hs;              // dword col, lanes consecutive
    float fA[16], fB[16];
    #pragma unroll
    for (int k = 0; k < 16; ++k) {
      const float2 e = __half22float2(u2h(SP[PITCHD * (16 * g + k) + cd]));
      fA[k] = e.x; fB[k] = e.y;
    }
    fwht16(fA); fwht16(fB);
    #pragma unroll
    for (int k = 0; k < 16; ++k)
      SP[PITCHD * (16 * g + k) + cd] = h2u(__floats2half2_rn(fA[k], fB[k]));
  }
  __syncthreads();

  // ---- P4: fwht16 over h1 -> xSC (f2 done) -> g -> fwht16 over h1 -> xSC ----
  // == round-8 pass B (proven 0-conflict, 52 VGPR). LDS half-col c == w.
  {
    __half* Sh = reinterpret_cast<__half*>(SP);
    const int c   = tid & 255;
    const int grp = tid >> 8;
    float f[16];
    #pragma unroll 1
    for (int gg = grp; gg < 16; gg += 4) {
      #pragma unroll
      for (int a = 0; a < 16; ++a)
        f[a] = __half2float(Sh[(gg + 16 * a) * (2 * PITCHD) + c]);
      fwht16(f);
      #pragma unroll
      for (int a = 0; a < 16; ++a) f[a] *= SC;

      #pragma unroll 4
      for (int a = 0; a < 16; ++a) {
        const int off = (gg + 16 * a) * 256 + c;   // global pitch 256
        float acc = 0.f;
        #pragma unroll
        for (int p = 0; p < 4; ++p) {
          const float2 w = __half22float2(u2h(W[p * NPX + off]));  // (v, |T|)
          acc += g_term(f[a] * w.x, w.y);
        }
        f[a] = acc;
      }

      fwht16(f);
      #pragma unroll
      for (int a = 0; a < 16; ++a)
        Sh[(gg + 16 * a) * (2 * PITCHD) + c] = __float2half_rn(f[a] * SC);
    }
  }
  __syncthreads();

  // ---- P5: fwht16 over h0 (inverse), no scale ----
  #pragma unroll 1
  for (int hs = 0; hs < 2; ++hs) {
    const int cd = q + 64 * hs;
    float fA[16], fB[16];
    #pragma unroll
    for (int k = 0; k < 16; ++k) {
      const float2 e = __half22float2(u2h(SP[PITCHD * (16 * g + k) + cd]));
      fA[k] = e.x; fB[k] = e.y;
    }
    fwht16(fA); fwht16(fB);
    #pragma unroll
    for (int k = 0; k < 16; ++k)
      SP[PITCHD * (16 * g + k) + cd] = h2u(__floats2half2_rn(fA[k], fB[k]));
  }
  __syncthreads();

  // ---- P6: fwht16 over w1 (inverse), no scale (SC folded into P7) ----
  {
    const int h = tid & 255;
    #pragma unroll 1
    for (int it = 0; it < 2; ++it) {
      const int c = (tid >> 8) + 4 * it;
      unsigned int* sp = SP + PITCHD * h + c;
      float fA[16], fB[16];
      #pragma unroll
      for (int a = 0; a < 16; ++a) {
        const float2 e = __half22float2(u2h(sp[8 * a]));
        fA[a] = e.x; fB[a] = e.y;
      }
      fwht16(fA); fwht16(fB);
      #pragma unroll
      for (int a = 0; a < 16; ++a)
        sp[8 * a] = h2u(__floats2half2_rn(fA[a], fB[a]));
    }
  }
  __syncthreads();

  // ---- P7: fwht16 over w0 (inverse) * SC + x residual -> out ----
  {
    const int h  = tid & 255;
    const int qq = tid >> 8;
    #pragma unroll 1
    for (int it = 0; it < 4; ++it) {
      const int w1 = qq * 4 + it;
      const unsigned int* sp = SP + PITCHD * h + 8 * w1;
      float f[16];
      #pragma unroll
      for (int j = 0; j < 8; ++j) {
        const float2 e = __half22float2(u2h(sp[j]));
        f[2*j] = e.x; f[2*j+1] = e.y;
      }
      fwht16(f);
      const float* xp = x + pbase + 256 * h + 16 * w1;
      float* op = out + pbase + 256 * h + 16 * w1;
      #pragma unroll
      for (int j = 0; j < 4; ++j) {
        const float4 xv = *reinterpret_cast<const float4*>(xp + 4 * j);
        float4 o;
        o.x = fmaf(f[4*j],     SC, xv.x);
        o.y = fmaf(f[4*j + 1], SC, xv.y);
        o.z = fmaf(f[4*j + 2], SC, xv.z);
        o.w = fmaf(f[4*j + 3], SC, xv.w);
        *reinterpret_cast<float4*>(op + 4 * j) = o;
      }
    }
  }
}

extern "C" void kernel_launch(void* const* d_in, const int* in_sizes, int n_in,
                              void* d_out, int out_size, void* d_ws, size_t ws_size,
                              hipStream_t stream) {
  const float* x = (const float*)d_in[0];
  const float* v = (const float*)d_in[1];
  const float* T = (const float*)d_in[2];
  float* out = (float*)d_out;
  unsigned int* W = (unsigned int*)d_ws;   // 1 MB packed (v,|T|) fp16

  k_prep<<<256, 256, 0, stream>>>(v, T, W);
  k_fused<<<512, 1024, 0, stream>>>(x, W, out);
}

// Round 13
// 181.271 us; speedup vs baseline: 1.5626x; 1.5626x over previous
//
#include <hip/hip_runtime.h>
#include <hip/hip_fp16.h>

// WHTConv2D fused: out = Rw(Rh(g(Rh(Rw(x))))) + x ; Rw/Rh = normalized FWHT-256.
// x: (8,64,256,256) f32 -> 512 planes. One 1024-thread block per plane, plane
// staged in LDS fp16, odd pitch 129 dwords/row (129 KiB). v,T pre-packed fp16.
//
// Round-13: shuffle-free 9-pass register-radix structure with FULLY COALESCED
// global access. Round 12 proved conflicts were irrelevant (0 conflicts, still
// 308 us): the regression was uncoalesced P1/P7 (lanes at 1KB stride -> 64
// scattered 16B requests/instr). Here:
//   P1: coalesced x -> fp16 LDS copy (no transform)     [= round-8 pattern]
//   P2: w0-fwd   (lane-consecutive rows, 2/bank)        [same-wave after P1]
//   P3: w1-fwd xSC (stride-8 dwords, 2/bank)
//   P4: h0-fwd   (lane-consecutive cols)                [round-12 P3, 0-conflict]
//   P5: h1-fwd xSC -> g -> h1-inv xSC (u16 cols; w==c)  [round-8 pass B, proven]
//   P6: h0-inv | P7: w1-inv xSC | P8: w0-inv (remapped) [same-wave before P9]
//   P9: coalesced LDS read + x residual -> out
// DS ~540 instr/thread (vs r11's ~930 incl 640 serial ds_swizzle), 0 shuffles.
// Scales at P3/P5a/P5c/P7 keep every fp16 intermediate O(1..100).

#define NPX 65536   // pixels per plane (global pitch 256)
#define PD  129     // LDS dwords per row (odd -> bank = (row+col)%32)
#define SC  0.0625f // 1/sqrt(256)

__device__ __forceinline__ unsigned int h2u(__half2 h) {
  union { __half2 h; unsigned int u; } c; c.h = h; return c.u;
}
__device__ __forceinline__ __half2 u2h(unsigned int u) {
  union { __half2 h; unsigned int u; } c; c.u = u; return c.h;
}

// 16-point unnormalized FWHT fully in registers.
__device__ __forceinline__ void fwht16(float f[16]) {
  #pragma unroll
  for (int d = 1; d < 16; d <<= 1) {
    #pragma unroll
    for (int i = 0; i < 16; ++i) {
      if (!(i & d)) {
        float a = f[i], b = f[i | d];
        f[i]     = a + b;
        f[i | d] = a - b;
      }
    }
  }
}

// g term with signed tanh: tanh(a)*relu(|a|-absT)
__device__ __forceinline__ float g_term(float a, float absT) {
  float e  = __builtin_amdgcn_exp2f(a * 2.8853900817779268f);  // exp(2a)
  float th = 1.0f - 2.0f * __builtin_amdgcn_rcpf(e + 1.0f);    // tanh(a)
  float rl = fmaxf(fabsf(a) - absT, 0.0f);                     // fabs = src mod
  return th * rl;
}

// ---- prep: W[p][pix] = half2(v, |T|) packed in one u32 ----
__global__ __launch_bounds__(256) void k_prep(const float* __restrict__ v,
                                              const float* __restrict__ T,
                                              unsigned int* __restrict__ W) {
  const int i = 4 * (blockIdx.x * 256 + threadIdx.x);
  const float4 v4 = *reinterpret_cast<const float4*>(v + i);
  const float4 t4 = *reinterpret_cast<const float4*>(T + i);
  uint4 w;
  w.x = h2u(__floats2half2_rn(v4.x, fabsf(t4.x)));
  w.y = h2u(__floats2half2_rn(v4.y, fabsf(t4.y)));
  w.z = h2u(__floats2half2_rn(v4.z, fabsf(t4.z)));
  w.w = h2u(__floats2half2_rn(v4.w, fabsf(t4.w)));
  *reinterpret_cast<uint4*>(W + i) = w;
}

__global__ __launch_bounds__(1024) void k_fused(const float* __restrict__ x,
                                                const unsigned int* __restrict__ W,
                                                float* __restrict__ out) {
  __shared__ __align__(16) unsigned int SP[256 * PD];   // 129 KiB
  const int tid  = threadIdx.x;
  const int lane = tid & 63;
  const int wv   = tid >> 6;
  const size_t pbase = (size_t)blockIdx.x * NPX;

  // ---- P1: coalesced x -> fp16 LDS (no transform) ----
  #pragma unroll 2
  for (int rr = 0; rr < 16; ++rr) {
    const int row = wv * 16 + rr;
    const float4 xv = *reinterpret_cast<const float4*>(x + pbase + (size_t)row * 256 + 4 * lane);
    uint2 pk;
    pk.x = h2u(__floats2half2_rn(xv.x, xv.y));
    pk.y = h2u(__floats2half2_rn(xv.z, xv.w));
    *reinterpret_cast<uint2*>(SP + PD * row + 2 * lane) = pk;
  }
  // no barrier: P2 wave wv reads only rows 16wv..16wv+15 (this wave's writes)

  // ---- P2: w0-fwd (fwht16 over u at fixed s); h = 16wv + (lane&15) ----
  {
    const int h = 16 * wv + (lane & 15);
    #pragma unroll 1
    for (int it = 0; it < 4; ++it) {
      const int s = (lane >> 4) + 4 * it;     // 0..15
      unsigned int* sp = SP + PD * h + 8 * s;
      float f[16];
      #pragma unroll
      for (int j = 0; j < 8; ++j) {
        const float2 e = __half22float2(u2h(sp[j]));
        f[2*j] = e.x; f[2*j+1] = e.y;
      }
      fwht16(f);
      #pragma unroll
      for (int j = 0; j < 8; ++j)
        sp[j] = h2u(__floats2half2_rn(f[2*j], f[2*j+1]));
    }
  }
  __syncthreads();

  // ---- P3: w1-fwd xSC (fwht16 over s at fixed u-pair j); stride-8 dwords ----
  {
    const int h = tid & 255;
    #pragma unroll 1
    for (int it = 0; it < 2; ++it) {
      const int j = (tid >> 8) + 4 * it;      // 0..7
      unsigned int* sp = SP + PD * h + j;
      float fA[16], fB[16];
      #pragma unroll
      for (int a = 0; a < 16; ++a) {
        const float2 e = __half22float2(u2h(sp[8 * a]));
        fA[a] = e.x; fB[a] = e.y;
      }
      fwht16(fA); fwht16(fB);
      #pragma unroll
      for (int a = 0; a < 16; ++a)
        sp[8 * a] = h2u(__floats2half2_rn(fA[a] * SC, fB[a] * SC));
    }
  }
  __syncthreads();

  // ---- P4: h0-fwd (rows 16g+k at dword col cd) ----
  const int q = tid & 63, g = tid >> 6;
  #pragma unroll 1
  for (int hs = 0; hs < 2; ++hs) {
    const int cd = q + 64 * hs;
    float fA[16], fB[16];
    #pragma unroll
    for (int k = 0; k < 16; ++k) {
      const float2 e = __half22float2(u2h(SP[PD * (16 * g + k) + cd]));
      fA[k] = e.x; fB[k] = e.y;
    }
    fwht16(fA); fwht16(fB);
    #pragma unroll
    for (int k = 0; k < 16; ++k)
      SP[PD * (16 * g + k) + cd] = h2u(__floats2half2_rn(fA[k], fB[k]));
  }
  __syncthreads();

  // ---- P5: h1-fwd xSC -> g -> h1-inv xSC (u16 col c; LDS half-col == w) ----
  {
    __half* Sh = reinterpret_cast<__half*>(SP);
    const int c   = tid & 255;
    const int grp = tid >> 8;
    float f[16];
    #pragma unroll 1
    for (int gg = grp; gg < 16; gg += 4) {
      #pragma unroll
      for (int a = 0; a < 16; ++a)
        f[a] = __half2float(Sh[(gg + 16 * a) * (2 * PD) + c]);
      fwht16(f);
      #pragma unroll
      for (int a = 0; a < 16; ++a) f[a] *= SC;

      #pragma unroll 4
      for (int a = 0; a < 16; ++a) {
        const int off = (gg + 16 * a) * 256 + c;   // global pitch 256
        float acc = 0.f;
        #pragma unroll
        for (int p = 0; p < 4; ++p) {
          const float2 w = __half22float2(u2h(W[p * NPX + off]));  // (v, |T|)
          acc += g_term(f[a] * w.x, w.y);
        }
        f[a] = acc;
      }

      fwht16(f);
      #pragma unroll
      for (int a = 0; a < 16; ++a)
        Sh[(gg + 16 * a) * (2 * PD) + c] = __float2half_rn(f[a] * SC);
    }
  }
  __syncthreads();

  // ---- P6: h0-inv (no scale) ----
  #pragma unroll 1
  for (int hs = 0; hs < 2; ++hs) {
    const int cd = q + 64 * hs;
    float fA[16], fB[16];
    #pragma unroll
    for (int k = 0; k < 16; ++k) {
      const float2 e = __half22float2(u2h(SP[PD * (16 * g + k) + cd]));
      fA[k] = e.x; fB[k] = e.y;
    }
    fwht16(fA); fwht16(fB);
    #pragma unroll
    for (int k = 0; k < 16; ++k)
      SP[PD * (16 * g + k) + cd] = h2u(__floats2half2_rn(fA[k], fB[k]));
  }
  __syncthreads();

  // ---- P7: w1-inv xSC ----
  {
    const int h = tid & 255;
    #pragma unroll 1
    for (int it = 0; it < 2; ++it) {
      const int j = (tid >> 8) + 4 * it;
      unsigned int* sp = SP + PD * h + j;
      float fA[16], fB[16];
      #pragma unroll
      for (int a = 0; a < 16; ++a) {
        const float2 e = __half22float2(u2h(sp[8 * a]));
        fA[a] = e.x; fB[a] = e.y;
      }
      fwht16(fA); fwht16(fB);
      #pragma unroll
      for (int a = 0; a < 16; ++a)
        sp[8 * a] = h2u(__floats2half2_rn(fA[a] * SC, fB[a] * SC));
    }
  }
  __syncthreads();

  // ---- P8: w0-inv (no scale); remapped for same-wave handoff to P9 ----
  {
    const int h = 16 * wv + (lane & 15);
    #pragma unroll 1
    for (int it = 0; it < 4; ++it) {
      const int s = (lane >> 4) + 4 * it;
      unsigned int* sp = SP + PD * h + 8 * s;
      float f[16];
      #pragma unroll
      for (int j = 0; j < 8; ++j) {
        const float2 e = __half22float2(u2h(sp[j]));
        f[2*j] = e.x; f[2*j+1] = e.y;
      }
      fwht16(f);
      #pragma unroll
      for (int j = 0; j < 8; ++j)
        sp[j] = h2u(__floats2half2_rn(f[2*j], f[2*j+1]));
    }
  }
  // no barrier: P9 wave wv reads only rows 16wv..16wv+15 (this wave's writes)

  // ---- P9: coalesced LDS read + x residual -> out ----
  #pragma unroll 2
  for (int rr = 0; rr < 16; ++rr) {
    const int row = wv * 16 + rr;
    const uint2 pk = *reinterpret_cast<const uint2*>(SP + PD * row + 2 * lane);
    const float2 lo = __half22float2(u2h(pk.x));
    const float2 hi = __half22float2(u2h(pk.y));
    const float4 xv = *reinterpret_cast<const float4*>(x + pbase + (size_t)row * 256 + 4 * lane);
    float4 o;
    o.x = lo.x + xv.x;
    o.y = lo.y + xv.y;
    o.z = hi.x + xv.z;
    o.w = hi.y + xv.w;
    *reinterpret_cast<float4*>(out + pbase + (size_t)row * 256 + 4 * lane) = o;
  }
}

extern "C" void kernel_launch(void* const* d_in, const int* in_sizes, int n_in,
                              void* d_out, int out_size, void* d_ws, size_t ws_size,
                              hipStream_t stream) {
  const float* x = (const float*)d_in[0];
  const float* v = (const float*)d_in[1];
  const float* T = (const float*)d_in[2];
  float* out = (float*)d_out;
  unsigned int* W = (unsigned int*)d_ws;   // 1 MB packed (v,|T|) fp16

  k_prep<<<256, 256, 0, stream>>>(v, T, W);
  k_fused<<<512, 1024, 0, stream>>>(x, W, out);
}

// Round 14
// 171.227 us; speedup vs baseline: 1.6542x; 1.0587x over previous
//
#include <hip/hip_runtime.h>
#include <hip/hip_fp16.h>

// WHTConv2D fused: out = Rw(Rh(g(Rh(Rw(x))))) + x ; Rw/Rh = normalized FWHT-256.
// x: (8,64,256,256) f32 -> 512 planes. One 1024-thread block per TWO planes
// (grid 256, all blocks resident). Plane staged in LDS fp16 (128 KB, pitch 256).
// v,T pre-packed (v,|T|) fp16 in d_ws by k_prep.
//
// Round-14: round-11 structure (best verified: 168.7 us, 0 conflicts, no spill)
// + cross-plane software pipelining. Each block processes planes 2b, 2b+1
// sequentially; the plane boundary has NO barrier (phase-3 of plane 1 and
// phase-1 of plane 2 touch only the wave's own 16 LDS rows -> same-wave
// in-order DS, verified idiom from round 11). This removes the two-round
// dispatch serialization (512 blocks / 256 CUs) and lets plane-1's store tail
// overlap plane-2's load/shuffle head. 2 barriers per plane (cross-wave
// transposes) remain. Rounds 12/13 falsified the shuffle-DS and bank-conflict
// theories (re-structures plateaued 186-205); the invariant is phase-serial
// pipe usage + tail, attacked here.

#define NPX 65536   // pixels per plane
#define SC  0.0625f // 1/sqrt(256)

__device__ __forceinline__ unsigned int h2u(__half2 h) {
  union { __half2 h; unsigned int u; } c; c.h = h; return c.u;
}
__device__ __forceinline__ __half2 u2h(unsigned int u) {
  union { __half2 h; unsigned int u; } c; c.u = u; return c.h;
}

// 16-point unnormalized FWHT fully in registers.
__device__ __forceinline__ void fwht16(float f[16]) {
  #pragma unroll
  for (int d = 1; d < 16; d <<= 1) {
    #pragma unroll
    for (int i = 0; i < 16; ++i) {
      if (!(i & d)) {
        float a = f[i], b = f[i | d];
        f[i]     = a + b;
        f[i | d] = a - b;
      }
    }
  }
}

// 256-point unnormalized FWHT across one wave; lane holds elems i = 4*lane + j.
__device__ __forceinline__ void fwht256_wave(float r[4], int lane) {
  float a0 = r[0] + r[1], b0 = r[0] - r[1];
  float a1 = r[2] + r[3], b1 = r[2] - r[3];
  r[0] = a0 + a1; r[1] = b0 + b1; r[2] = a0 - a1; r[3] = b0 - b1;
  #pragma unroll
  for (int m = 1; m <= 32; m <<= 1) {
    const float s = (lane & m) ? -1.0f : 1.0f;
    #pragma unroll
    for (int j = 0; j < 4; ++j) {
      float t = __shfl_xor(r[j], m);
      r[j] = fmaf(r[j], s, t);   // low lane: r+t ; high lane: t-r
    }
  }
}

// g term with signed tanh: tanh(a)*relu(|a|-absT)
__device__ __forceinline__ float g_term(float a, float absT) {
  float e  = __builtin_amdgcn_exp2f(a * 2.8853900817779268f);  // exp(2a)
  float th = 1.0f - 2.0f * __builtin_amdgcn_rcpf(e + 1.0f);    // tanh(a)
  float rl = fmaxf(fabsf(a) - absT, 0.0f);                     // fabs = src mod
  return th * rl;
}

// ---- prep: W[p][pix] = half2(v, |T|) packed in one u32 ----
__global__ __launch_bounds__(256) void k_prep(const float* __restrict__ v,
                                              const float* __restrict__ T,
                                              unsigned int* __restrict__ W) {
  const int i = 4 * (blockIdx.x * 256 + threadIdx.x);
  const float4 v4 = *reinterpret_cast<const float4*>(v + i);
  const float4 t4 = *reinterpret_cast<const float4*>(T + i);
  uint4 w;
  w.x = h2u(__floats2half2_rn(v4.x, fabsf(t4.x)));
  w.y = h2u(__floats2half2_rn(v4.y, fabsf(t4.y)));
  w.z = h2u(__floats2half2_rn(v4.z, fabsf(t4.z)));
  w.w = h2u(__floats2half2_rn(v4.w, fabsf(t4.w)));
  *reinterpret_cast<uint4*>(W + i) = w;
}

__global__ __launch_bounds__(1024) void k_fused(const float* __restrict__ x,
                                                const unsigned int* __restrict__ W,
                                                float* __restrict__ out) {
  __shared__ __half S[256 * 256];          // 128 KiB static, pitch 256
  const int tid  = threadIdx.x;
  const int lane = tid & 63;
  const int wv   = tid >> 6;               // wave id 0..15
  const int q    = tid & 63;               // passes A/C column pair base
  const int g    = tid >> 6;               // passes A/C row group (== wv)
  const int c    = tid & 255;              // pass B single column
  const int grp  = tid >> 8;               // pass B g-subset

  #pragma unroll 1
  for (int pl = 0; pl < 2; ++pl) {
    const size_t pbase = ((size_t)blockIdx.x * 2 + pl) * NPX;

    // ---- phase 1: row FWHT of x -> LDS (fp16, x SC) ----
    // No barrier before (plane 2: this wave's rows were last touched by this
    // wave's own phase-3 reads of plane 1 -> same-wave in-order DS).
    #pragma unroll 2
    for (int rr = 0; rr < 16; ++rr) {
      const int row = wv * 16 + rr;
      const float4 xv = *reinterpret_cast<const float4*>(x + pbase + (size_t)row * 256 + 4 * lane);
      float r[4] = {xv.x, xv.y, xv.z, xv.w};
      fwht256_wave(r, lane);
      uint2 pk;
      pk.x = h2u(__floats2half2_rn(r[0] * SC, r[1] * SC));
      pk.y = h2u(__floats2half2_rn(r[2] * SC, r[3] * SC));
      *reinterpret_cast<uint2*>(&S[row * 256 + 4 * lane]) = pk;
    }
    // no barrier: pass A (wave g) reads only rows 16g..16g+15 (own writes)

    // pass A: FWHT16 over k (contiguous rows 16g+k); two half-sweeps, b32 LDS
    {
      float fp[2][16];
      #pragma unroll 1
      for (int hs = 0; hs < 2; ++hs) {
        const int cb = 2 * q + 128 * hs;
        #pragma unroll
        for (int k = 0; k < 16; ++k) {
          unsigned int d = *reinterpret_cast<unsigned int*>(&S[(16 * g + k) * 256 + cb]);
          float2 e = __half22float2(u2h(d));
          fp[0][k] = e.x; fp[1][k] = e.y;
        }
        fwht16(fp[0]); fwht16(fp[1]);
        #pragma unroll
        for (int k = 0; k < 16; ++k) {
          *reinterpret_cast<unsigned int*>(&S[(16 * g + k) * 256 + cb]) =
              h2u(__floats2half2_rn(fp[0][k], fp[1][k]));
        }
      }
    }
    __syncthreads();   // cross-wave: pass B reads all row groups

    // pass B: rows gg+16a: FWHT16 over a (completes Rh1) -> xSC -> g ->
    // FWHT16 over a (first half of Rh2) -> xSC -> back to LDS.
    {
      float f[16];
      #pragma unroll 1
      for (int gg = grp; gg < 16; gg += 4) {
        #pragma unroll
        for (int a = 0; a < 16; ++a)
          f[a] = __half2float(S[(gg + 16 * a) * 256 + c]);
        fwht16(f);
        #pragma unroll
        for (int a = 0; a < 16; ++a) f[a] *= SC;

        #pragma unroll 4
        for (int a = 0; a < 16; ++a) {
          const int off = (gg + 16 * a) * 256 + c;
          float acc = 0.f;
          #pragma unroll
          for (int p = 0; p < 4; ++p) {
            const float2 w = __half22float2(u2h(W[p * NPX + off]));  // (v, |T|)
            acc += g_term(f[a] * w.x, w.y);
          }
          f[a] = acc;
        }

        fwht16(f);
        #pragma unroll
        for (int a = 0; a < 16; ++a)
          S[(gg + 16 * a) * 256 + c] = __float2half_rn(f[a] * SC);
      }
    }
    __syncthreads();   // cross-wave: pass C reads all row groups

    // pass C: FWHT16 over k (second half of Rh2; scale already applied)
    {
      float fp[2][16];
      #pragma unroll 1
      for (int hs = 0; hs < 2; ++hs) {
        const int cb = 2 * q + 128 * hs;
        #pragma unroll
        for (int k = 0; k < 16; ++k) {
          unsigned int d = *reinterpret_cast<unsigned int*>(&S[(16 * g + k) * 256 + cb]);
          float2 e = __half22float2(u2h(d));
          fp[0][k] = e.x; fp[1][k] = e.y;
        }
        fwht16(fp[0]); fwht16(fp[1]);
        #pragma unroll
        for (int k = 0; k < 16; ++k) {
          *reinterpret_cast<unsigned int*>(&S[(16 * g + k) * 256 + cb]) =
              h2u(__floats2half2_rn(fp[0][k], fp[1][k]));
        }
      }
    }
    // no barrier: phase 3 (wave wv) reads only rows 16wv..16wv+15 (own writes)

    // ---- phase 3: row FWHT (x SC) + x residual -> out ----
    #pragma unroll 2
    for (int rr = 0; rr < 16; ++rr) {
      const int row = wv * 16 + rr;
      uint2 pk = *reinterpret_cast<uint2*>(&S[row * 256 + 4 * lane]);
      float2 lo = __half22float2(u2h(pk.x));
      float2 hi = __half22float2(u2h(pk.y));
      float r[4] = {lo.x, lo.y, hi.x, hi.y};
      fwht256_wave(r, lane);
      const float4 xv = *reinterpret_cast<const float4*>(x + pbase + (size_t)row * 256 + 4 * lane);
      float4 o;
      o.x = fmaf(r[0], SC, xv.x);
      o.y = fmaf(r[1], SC, xv.y);
      o.z = fmaf(r[2], SC, xv.z);
      o.w = fmaf(r[3], SC, xv.w);
      *reinterpret_cast<float4*>(out + pbase + (size_t)row * 256 + 4 * lane) = o;
    }
    // no barrier at plane boundary (see phase-1 comment)
  }
}

extern "C" void kernel_launch(void* const* d_in, const int* in_sizes, int n_in,
                              void* d_out, int out_size, void* d_ws, size_t ws_size,
                              hipStream_t stream) {
  const float* x = (const float*)d_in[0];
  const float* v = (const float*)d_in[1];
  const float* T = (const float*)d_in[2];
  float* out = (float*)d_out;
  unsigned int* W = (unsigned int*)d_ws;   // 1 MB packed (v,|T|) fp16

  k_prep<<<256, 256, 0, stream>>>(v, T, W);
  k_fused<<<256, 1024, 0, stream>>>(x, W, out);
}